// Round 1
// baseline (316.628 us; speedup 1.0000x reference)
//
#include <hip/hip_runtime.h>
#include <hip/hip_bf16.h>
#include <cstddef>

#define N_NODES 65536
#define P_PATCH 1024
#define E_EDGES 16384
#define DD      64
#define EPSF    1e-6f

// ---------------- setup kernels ----------------

__global__ void patch_bounds_kernel(const int* __restrict__ batch, int* __restrict__ start) {
    int i = blockIdx.x * blockDim.x + threadIdx.x;
    if (i >= N_NODES) return;
    int b  = batch[i];
    int bp = (i == 0) ? -1 : batch[i - 1];
    for (int p = bp + 1; p <= b; ++p) start[p] = i;
    if (i == N_NODES - 1) {
        for (int p = b + 1; p <= P_PATCH; ++p) start[p] = N_NODES;
    }
}

__global__ void edge_hist_kernel(const int* __restrict__ row, const float* __restrict__ attr,
                                 float* __restrict__ deg, int* __restrict__ rowcnt) {
    int e = blockIdx.x * blockDim.x + threadIdx.x;
    if (e >= E_EDGES) return;
    int r = row[e];
    atomicAdd(&deg[r], attr[e]);
    atomicAdd(&rowcnt[r], 1);
}

__global__ void scan_dinv_kernel(const int* __restrict__ rowcnt, int* __restrict__ row_start,
                                 const float* __restrict__ deg, float* __restrict__ dinv) {
    __shared__ int s[P_PATCH];
    int t = threadIdx.x;
    s[t] = rowcnt[t];
    float dg = deg[t];
    dinv[t] = (dg > 0.f) ? rsqrtf(fmaxf(dg, EPSF)) : 0.f;
    __syncthreads();
    for (int off = 1; off < P_PATCH; off <<= 1) {
        int v = (t >= off) ? s[t - off] : 0;
        __syncthreads();
        s[t] += v;
        __syncthreads();
    }
    row_start[t + 1] = s[t];
    if (t == 0) row_start[0] = 0;
}

__global__ void edge_scatter_kernel(const int* __restrict__ row, const int* __restrict__ row_start,
                                    int* __restrict__ rowfill, int* __restrict__ edge_perm) {
    int e = blockIdx.x * blockDim.x + threadIdx.x;
    if (e >= E_EDGES) return;
    int r = row[e];
    int pos = row_start[r] + atomicAdd(&rowfill[r], 1);
    edge_perm[pos] = e;
}

// ---------------- fused MLP / GEMM kernel ----------------
template <bool TWO, bool GATHER, bool RELU_OUT>
__global__ void mlp_kernel(const float* __restrict__ in, const int* __restrict__ gmap,
                           const float* __restrict__ W1, const float* __restrict__ b1,
                           const float* __restrict__ W2, const float* __restrict__ b2,
                           float* __restrict__ out) {
    __shared__ float W1s[64 * 64];
    __shared__ float W2s[TWO ? 64 * 64 : 1];
    __shared__ float xs[64 * 65];
    __shared__ float b1s[64], b2s[64];

    int t = threadIdx.x;
    for (int i = t; i < 4096; i += 256) {
        W1s[i] = W1[i];
        if (TWO) W2s[i] = W2[i];
    }
    if (t < 64) {
        b1s[t] = b1[t];
        if (TWO) b2s[t] = b2[t];
    }

    int row0 = blockIdx.x * 64;
    int r  = t >> 2;
    int c0 = (t & 3) * 16;
    int grow = row0 + r;
    int srow = GATHER ? gmap[grow] : grow;

    const float4* src = (const float4*)(in + (size_t)srow * DD + c0);
    float4 x0 = src[0], x1 = src[1], x2 = src[2], x3 = src[3];
    float* xd = &xs[r * 65 + c0];
    xd[0]=x0.x; xd[1]=x0.y; xd[2]=x0.z; xd[3]=x0.w;
    xd[4]=x1.x; xd[5]=x1.y; xd[6]=x1.z; xd[7]=x1.w;
    xd[8]=x2.x; xd[9]=x2.y; xd[10]=x2.z; xd[11]=x2.w;
    xd[12]=x3.x; xd[13]=x3.y; xd[14]=x3.z; xd[15]=x3.w;
    __syncthreads();

    float acc[16];
#pragma unroll
    for (int j = 0; j < 16; ++j) acc[j] = 0.f;
    for (int k = 0; k < 64; ++k) {
        float xv = xs[r * 65 + k];
        const float* wrow = &W1s[k * 64 + c0];
#pragma unroll
        for (int j = 0; j < 16; ++j) acc[j] = fmaf(xv, wrow[j], acc[j]);
    }
#pragma unroll
    for (int j = 0; j < 16; ++j) {
        float v = acc[j] + b1s[c0 + j];
        if (TWO) v = fmaxf(v, 0.f);
        else if (RELU_OUT) v = fmaxf(v, 0.f);
        acc[j] = v;
    }

    if (TWO) {
        __syncthreads();
        float* xd2 = &xs[r * 65 + c0];
#pragma unroll
        for (int j = 0; j < 16; ++j) xd2[j] = acc[j];
        __syncthreads();
#pragma unroll
        for (int j = 0; j < 16; ++j) acc[j] = 0.f;
        for (int k = 0; k < 64; ++k) {
            float xv = xs[r * 65 + k];
            const float* wrow = &W2s[k * 64 + c0];
#pragma unroll
            for (int j = 0; j < 16; ++j) acc[j] = fmaf(xv, wrow[j], acc[j]);
        }
#pragma unroll
        for (int j = 0; j < 16; ++j) {
            float v = acc[j] + b2s[c0 + j];
            if (RELU_OUT) v = fmaxf(v, 0.f);
            acc[j] = v;
        }
    }

    float* dst = out + (size_t)grow * DD + c0;
#pragma unroll
    for (int j = 0; j < 16; ++j) dst[j] = acc[j];
}

// ---------------- per-patch segment reductions ----------------
__global__ void patch_reduce_kernel(const float* __restrict__ Q, const float* __restrict__ K,
                                    const int* __restrict__ start,
                                    float* __restrict__ Qs_raw, float* __restrict__ Ksk) {
    int p = blockIdx.x, t = threadIdx.x;
    int i0 = start[p], i1 = start[p + 1];
    float qa = 0.f, ka = 0.f;
    for (int i = i0; i < i1; ++i) {
        qa += Q[(size_t)i * DD + t];
        ka += K[(size_t)i * DD + t];
    }
    Qs_raw[p * DD + t] = qa;
    int cnt = i1 - i0;
    float km = ka / (float)max(cnt, 1);
    Ksk[p * DD + t] = fmaxf(km, 0.f);
}

__global__ void outer_kernel(const float* __restrict__ K, const float* __restrict__ V,
                             const int* __restrict__ start, float* __restrict__ M) {
    __shared__ float ks[4][64], vs[4][64];
    int p = blockIdx.x, t = threadIdx.x;
    int i0 = start[p], i1 = start[p + 1];
    int d  = t >> 2;
    int c0 = (t & 3) * 16;
    float acc[16];
#pragma unroll
    for (int j = 0; j < 16; ++j) acc[j] = 0.f;

    int n = t >> 6, c = t & 63;
    for (int i = i0; i < i1; i += 4) {
        int nn = min(4, i1 - i);
        if (n < nn) {
            ks[n][c] = fmaxf(K[(size_t)(i + n) * DD + c], 0.f);
            vs[n][c] = V[(size_t)(i + n) * DD + c];
        }
        __syncthreads();
        for (int q = 0; q < nn; ++q) {
            float kv = ks[q][d];
#pragma unroll
            for (int j = 0; j < 16; ++j) acc[j] = fmaf(kv, vs[q][c0 + j], acc[j]);
        }
        __syncthreads();
    }
    float* dst = &M[(size_t)p * 4096 + d * 64 + c0];
#pragma unroll
    for (int j = 0; j < 16; ++j) dst[j] = acc[j];
}

__global__ void prop_kernel(const float* __restrict__ M, const float* __restrict__ Ksk,
                            const float* __restrict__ attr, const int* __restrict__ colv,
                            const int* __restrict__ row_start, const int* __restrict__ edge_perm,
                            const float* __restrict__ dinv,
                            float* __restrict__ M2, float* __restrict__ Kagg) {
    int p = blockIdx.x, t = threadIdx.x;
    size_t base = (size_t)p * 4096 + (size_t)t * 16;
    float acc[16];
    {
        const float4* m0 = (const float4*)(M + base);
        float4 a0 = m0[0], a1 = m0[1], a2 = m0[2], a3 = m0[3];
        acc[0]=a0.x; acc[1]=a0.y; acc[2]=a0.z; acc[3]=a0.w;
        acc[4]=a1.x; acc[5]=a1.y; acc[6]=a1.z; acc[7]=a1.w;
        acc[8]=a2.x; acc[9]=a2.y; acc[10]=a2.z; acc[11]=a2.w;
        acc[12]=a3.x; acc[13]=a3.y; acc[14]=a3.z; acc[15]=a3.w;
    }
    float kacc = (t < 64) ? Ksk[p * DD + t] : 0.f;
    int e0 = row_start[p], e1 = row_start[p + 1];
    float dp = dinv[p];
    for (int ei = e0; ei < e1; ++ei) {
        int e = edge_perm[ei];
        int cidx = colv[e];
        float a = dp * attr[e] * dinv[cidx];
        const float4* mc = (const float4*)(M + (size_t)cidx * 4096 + (size_t)t * 16);
        float4 m0 = mc[0], m1 = mc[1], m2 = mc[2], m3 = mc[3];
        acc[0]=fmaf(a,m0.x,acc[0]);  acc[1]=fmaf(a,m0.y,acc[1]);
        acc[2]=fmaf(a,m0.z,acc[2]);  acc[3]=fmaf(a,m0.w,acc[3]);
        acc[4]=fmaf(a,m1.x,acc[4]);  acc[5]=fmaf(a,m1.y,acc[5]);
        acc[6]=fmaf(a,m1.z,acc[6]);  acc[7]=fmaf(a,m1.w,acc[7]);
        acc[8]=fmaf(a,m2.x,acc[8]);  acc[9]=fmaf(a,m2.y,acc[9]);
        acc[10]=fmaf(a,m2.z,acc[10]); acc[11]=fmaf(a,m2.w,acc[11]);
        acc[12]=fmaf(a,m3.x,acc[12]); acc[13]=fmaf(a,m3.y,acc[13]);
        acc[14]=fmaf(a,m3.z,acc[14]); acc[15]=fmaf(a,m3.w,acc[15]);
        if (t < 64) kacc = fmaf(a, Ksk[cidx * DD + t], kacc);
    }
    float4* dst = (float4*)(M2 + base);
    dst[0] = make_float4(acc[0], acc[1], acc[2], acc[3]);
    dst[1] = make_float4(acc[4], acc[5], acc[6], acc[7]);
    dst[2] = make_float4(acc[8], acc[9], acc[10], acc[11]);
    dst[3] = make_float4(acc[12], acc[13], acc[14], acc[15]);
    if (t < 64) Kagg[p * DD + t] = kacc;
}

__global__ void readout_kernel(const float* __restrict__ M2, const float* __restrict__ Qk,
                               const float* __restrict__ Kagg, float* __restrict__ outp) {
    __shared__ float qs[64], ks[64];
    int p = blockIdx.x, t = threadIdx.x;
    qs[t] = Qk[p * DD + t];
    ks[t] = Kagg[p * DD + t];
    __syncthreads();
    float den = 0.f;
    for (int d = 0; d < 64; ++d) den = fmaf(qs[d], ks[d], den);
    const float* Mp = M2 + (size_t)p * 4096;
    float num = 0.f;
    for (int d = 0; d < 64; ++d) num = fmaf(qs[d], Mp[d * 64 + t], num);
    outp[p * DD + t] = num / (den + EPSF);
}

__global__ void final_kernel(const float* __restrict__ outp, const float* __restrict__ seed,
                             const float* __restrict__ Wc1, const float* __restrict__ bc1,
                             const float* __restrict__ Wc2, const float* __restrict__ bc2,
                             float* __restrict__ logits) {
    __shared__ float s_sc[32];
    __shared__ float s_pool[64];
    __shared__ float s_c1[32];
    int b = blockIdx.x, t = threadIdx.x;
    const float* ob = outp + (size_t)b * 32 * DD;
    if (t < 32) {
        float acc = 0.f;
        for (int d = 0; d < 64; ++d) acc = fmaf(ob[t * DD + d], seed[d], acc);
        s_sc[t] = acc * 0.125f;
    }
    __syncthreads();
    if (t == 0) {
        float mx = -1e30f;
        for (int p = 0; p < 32; ++p) mx = fmaxf(mx, s_sc[p]);
        float sum = 0.f;
        for (int p = 0; p < 32; ++p) { float e = expf(s_sc[p] - mx); s_sc[p] = e; sum += e; }
        float inv = 1.f / sum;
        for (int p = 0; p < 32; ++p) s_sc[p] *= inv;
    }
    __syncthreads();
    float pa = 0.f;
    for (int p = 0; p < 32; ++p) pa = fmaf(s_sc[p], ob[p * DD + t], pa);
    s_pool[t] = pa;
    __syncthreads();
    if (t < 32) {
        float acc = bc1[t];
        for (int d = 0; d < 64; ++d) acc = fmaf(s_pool[d], Wc1[d * 32 + t], acc);
        s_c1[t] = fmaxf(acc, 0.f);
    }
    __syncthreads();
    if (t < 10) {
        float acc = bc2[t];
        for (int j = 0; j < 32; ++j) acc = fmaf(s_c1[j], Wc2[j * 10 + t], acc);
        logits[b * 10 + t] = acc;
    }
}

// ---------------- launch ----------------

extern "C" void kernel_launch(void* const* d_in, const int* in_sizes, int n_in,
                              void* d_out, int out_size, void* d_ws, size_t ws_size,
                              hipStream_t stream) {
    const float* x      = (const float*)d_in[0];
    const int*   mapper = (const int*)d_in[1];
    const int*   batch  = (const int*)d_in[2];
    const int*   e_row  = (const int*)d_in[3];
    const int*   e_col  = (const int*)d_in[4];
    const float* e_attr = (const float*)d_in[5];
    const float* Wt1 = (const float*)d_in[6],  *bt1 = (const float*)d_in[7];
    const float* Wt2 = (const float*)d_in[8],  *bt2 = (const float*)d_in[9];
    const float* Wpre1 = (const float*)d_in[10], *bpre1 = (const float*)d_in[11];
    const float* Wpre2 = (const float*)d_in[12], *bpre2 = (const float*)d_in[13];
    const float* Wpost1 = (const float*)d_in[14], *bpost1 = (const float*)d_in[15];
    const float* Wpost2 = (const float*)d_in[16], *bpost2 = (const float*)d_in[17];
    const float* Wk = (const float*)d_in[18], *bk = (const float*)d_in[19];
    const float* Wv = (const float*)d_in[20], *bv = (const float*)d_in[21];
    const float* seed = (const float*)d_in[22];
    const float* Wc1 = (const float*)d_in[23], *bc1 = (const float*)d_in[24];
    const float* Wc2 = (const float*)d_in[25], *bc2 = (const float*)d_in[26];
    float* logits = (float*)d_out;

    const size_t NF = (size_t)N_NODES * DD;
    float* ws = (float*)d_ws;
    float* A  = ws;              // h, later M2
    float* Bq = ws + NF;         // Q, later M
    float* Ck = ws + 2 * NF;     // K
    float* Dv = ws + 3 * NF;     // V
    float* Qs_raw = ws + 4 * NF;
    float* Qk     = Qs_raw + P_PATCH * DD;
    float* Ksk    = Qk + P_PATCH * DD;
    float* Kagg   = Ksk + P_PATCH * DD;
    float* outp   = Kagg + P_PATCH * DD;
    float* deg    = outp + P_PATCH * DD;
    int*   rowcnt = (int*)(deg + P_PATCH);
    int*   rowfill= rowcnt + P_PATCH;
    float* dinv   = (float*)(rowfill + P_PATCH);
    int* patch_start = (int*)(dinv + P_PATCH);
    int* row_start   = patch_start + P_PATCH + 1;
    int* edge_perm   = row_start + P_PATCH + 1;

    hipMemsetAsync(deg, 0, 3 * P_PATCH * sizeof(int), stream);

    patch_bounds_kernel<<<N_NODES / 256, 256, 0, stream>>>(batch, patch_start);
    edge_hist_kernel<<<E_EDGES / 256, 256, 0, stream>>>(e_row, e_attr, deg, rowcnt);
    scan_dinv_kernel<<<1, P_PATCH, 0, stream>>>(rowcnt, row_start, deg, dinv);
    edge_scatter_kernel<<<E_EDGES / 256, 256, 0, stream>>>(e_row, row_start, rowfill, edge_perm);

    mlp_kernel<true, false, true><<<N_NODES / 64, 256, 0, stream>>>(
        x, nullptr, Wt1, bt1, Wt2, bt2, A);
    mlp_kernel<true, true, false><<<N_NODES / 64, 256, 0, stream>>>(
        A, mapper, Wpre1, bpre1, Wpre2, bpre2, Bq);
    mlp_kernel<false, true, false><<<N_NODES / 64, 256, 0, stream>>>(
        A, mapper, Wk, bk, nullptr, nullptr, Ck);
    mlp_kernel<false, true, false><<<N_NODES / 64, 256, 0, stream>>>(
        A, mapper, Wv, bv, nullptr, nullptr, Dv);

    patch_reduce_kernel<<<P_PATCH, 64, 0, stream>>>(Bq, Ck, patch_start, Qs_raw, Ksk);
    mlp_kernel<true, false, true><<<P_PATCH / 64, 256, 0, stream>>>(
        Qs_raw, nullptr, Wpost1, bpost1, Wpost2, bpost2, Qk);

    outer_kernel<<<P_PATCH, 256, 0, stream>>>(Ck, Dv, patch_start, Bq);
    prop_kernel<<<P_PATCH, 256, 0, stream>>>(Bq, Ksk, e_attr, e_col, row_start, edge_perm,
                                             dinv, A, Kagg);
    readout_kernel<<<P_PATCH, 64, 0, stream>>>(A, Qk, Kagg, outp);
    final_kernel<<<32, 64, 0, stream>>>(outp, seed, Wc1, bc1, Wc2, bc2, logits);
}